// Round 2
// baseline (501.830 us; speedup 1.0000x reference)
//
#include <hip/hip_runtime.h>

#define NN 100000
#define NE 1600000
#define BN_EPS 1e-5f

typedef short s8v __attribute__((ext_vector_type(8)));
typedef float f4v __attribute__((ext_vector_type(4)));

__device__ __forceinline__ unsigned short f2bf(float f) {
  union { float f; unsigned u; } v; v.f = f;
  return (unsigned short)((v.u + 0x7FFFu + ((v.u >> 16) & 1u)) >> 16);
}

#define MFMA16(a, b, c) __builtin_amdgcn_mfma_f32_16x16x32_bf16((a), (b), (c), 0, 0, 0)

// ---------------------------------------------------------------------------
// x (f32) -> bf16 staging buffer (one-shot, so the per-edge gather is 16B loads)
// ---------------------------------------------------------------------------
__global__ __launch_bounds__(256) void cvt_kernel(
    const float* __restrict__ xf, unsigned short* __restrict__ xb)
{
  const size_t i = (size_t)blockIdx.x * blockDim.x + threadIdx.x;
  if (i * 4 >= (size_t)NN * 64) return;
  float4 v = ((const float4*)xf)[i];
  ushort4 o = make_ushort4(f2bf(v.x), f2bf(v.y), f2bf(v.z), f2bf(v.w));
  ((ushort4*)xb)[i] = o;
}

// ---------------------------------------------------------------------------
// Edge MLP: h2 = prelu(prelu(cat(x[dst],x[src]) @ W1 + b1) @ W2 + b2)
// agg[dst] += h2  (fp32 atomics)
// Per-wave tile: M=16 edges, K=128, N=64.  A-layout: A[m=lane&15][k=q*8+j]
// ---------------------------------------------------------------------------
__global__ __launch_bounds__(256) void edge_mlp_kernel(
    const unsigned short* __restrict__ xb,
    const int* __restrict__ ei,
    const float* __restrict__ W1, const float* __restrict__ b1,
    const float* __restrict__ a1p,
    const float* __restrict__ W2, const float* __restrict__ b2,
    const float* __restrict__ a2p,
    float* __restrict__ agg)
{
  const int lane = threadIdx.x & 63;
  const int wv   = threadIdx.x >> 6;
  const int q    = lane >> 4;
  const int r    = lane & 15;
  const int wpb  = blockDim.x >> 6;
  const int nw   = gridDim.x * wpb;
  const int wid  = blockIdx.x * wpb + wv;

  // Preload W1 (128x64) / W2 (64x64) as bf16 B-fragments: B[k=q*8+j][n=nt*16+r]
  s8v B1f[4][4];
  s8v B2f[2][4];
#pragma unroll
  for (int kk = 0; kk < 4; ++kk)
#pragma unroll
    for (int nt = 0; nt < 4; ++nt) {
      s8v f;
#pragma unroll
      for (int j = 0; j < 8; ++j)
        f[j] = (short)f2bf(W1[(kk * 32 + q * 8 + j) * 64 + nt * 16 + r]);
      B1f[kk][nt] = f;
    }
#pragma unroll
  for (int kk = 0; kk < 2; ++kk)
#pragma unroll
    for (int nt = 0; nt < 4; ++nt) {
      s8v f;
#pragma unroll
      for (int j = 0; j < 8; ++j)
        f[j] = (short)f2bf(W2[(kk * 32 + q * 8 + j) * 64 + nt * 16 + r]);
      B2f[kk][nt] = f;
    }

  float bias1[4], bias2[4];
#pragma unroll
  for (int nt = 0; nt < 4; ++nt) {
    bias1[nt] = b1[nt * 16 + r];
    bias2[nt] = b2[nt * 16 + r];
  }
  const float al1 = a1p[0];
  const float al2 = a2p[0];

  // per-wave transpose buffer: 16 rows x 64 cols, row stride 72 (16B-aligned)
  __shared__ __align__(16) unsigned short hbuf[4][16 * 72];
  unsigned short* hb = hbuf[wv];

  const int* __restrict__ srcp = ei;        // edge_index[0] = src (x_j)
  const int* __restrict__ dstp = ei + NE;   // edge_index[1] = dst (x_i)

  for (int t = wid; t < NE / 16; t += nw) {
    const int e  = t * 16 + r;
    const int dn = dstp[e];
    const int sn = srcp[e];
    const s8v* xd = (const s8v*)(xb + (size_t)dn * 64);
    const s8v* xs = (const s8v*)(xb + (size_t)sn * 64);
    s8v a0  = xd[q];       // k 0..31   -> x[dst]
    s8v a1v = xd[q + 4];   // k 32..63
    s8v a2v = xs[q];       // k 64..95  -> x[src]
    s8v a3v = xs[q + 4];   // k 96..127

    f4v acc[4];
#pragma unroll
    for (int nt = 0; nt < 4; ++nt) {
      f4v c = {0.0f, 0.0f, 0.0f, 0.0f};
      c = MFMA16(a0,  B1f[0][nt], c);
      c = MFMA16(a1v, B1f[1][nt], c);
      c = MFMA16(a2v, B1f[2][nt], c);
      c = MFMA16(a3v, B1f[3][nt], c);
      acc[nt] = c;
    }

    // bias + prelu, C-layout (row=q*4+rg, col=nt*16+r) -> LDS transpose
#pragma unroll
    for (int nt = 0; nt < 4; ++nt)
#pragma unroll
      for (int rg = 0; rg < 4; ++rg) {
        float v = acc[nt][rg] + bias1[nt];
        v = v >= 0.0f ? v : al1 * v;
        hb[(q * 4 + rg) * 72 + nt * 16 + r] = f2bf(v);
      }
    // A-layout readback: A[m=r][k=kk*32+q*8+j] (same wave, in-order DS pipe)
    s8v p0 = *(const s8v*)(hb + r * 72 + q * 8);
    s8v p1 = *(const s8v*)(hb + r * 72 + 32 + q * 8);

    f4v acc2[4];
#pragma unroll
    for (int nt = 0; nt < 4; ++nt) {
      f4v c = {0.0f, 0.0f, 0.0f, 0.0f};
      c = MFMA16(p0, B2f[0][nt], c);
      c = MFMA16(p1, B2f[1][nt], c);
      acc2[nt] = c;
    }

    int drow[4];
#pragma unroll
    for (int rg = 0; rg < 4; ++rg) drow[rg] = __shfl(dn, q * 4 + rg, 64);

#pragma unroll
    for (int nt = 0; nt < 4; ++nt)
#pragma unroll
      for (int rg = 0; rg < 4; ++rg) {
        float v = acc2[nt][rg] + bias2[nt];
        v = v >= 0.0f ? v : al2 * v;
        atomicAdd(&agg[(size_t)drow[rg] * 64 + nt * 16 + r], v);
      }
  }
}

// ---------------------------------------------------------------------------
// Node MLP: z = prelu(prelu(cat(x,agg) @ W3 + b3) @ W4 + b4, a_blk)
// writes z (f32) to d_out, accumulates BN partials (sum, sumsq) per feature
// ---------------------------------------------------------------------------
__global__ __launch_bounds__(256) void node_mlp_kernel(
    const unsigned short* __restrict__ xb,
    const float* __restrict__ agg,
    const float* __restrict__ W3, const float* __restrict__ b3,
    const float* __restrict__ a3p,
    const float* __restrict__ W4, const float* __restrict__ b4,
    const float* __restrict__ ablkp,
    float* __restrict__ zout,
    float* __restrict__ part)
{
  const int lane = threadIdx.x & 63;
  const int wv   = threadIdx.x >> 6;
  const int q    = lane >> 4;
  const int r    = lane & 15;
  const int wpb  = blockDim.x >> 6;
  const int nw   = gridDim.x * wpb;
  const int wid  = blockIdx.x * wpb + wv;

  s8v B3f[4][4];
  s8v B4f[2][4];
#pragma unroll
  for (int kk = 0; kk < 4; ++kk)
#pragma unroll
    for (int nt = 0; nt < 4; ++nt) {
      s8v f;
#pragma unroll
      for (int j = 0; j < 8; ++j)
        f[j] = (short)f2bf(W3[(kk * 32 + q * 8 + j) * 64 + nt * 16 + r]);
      B3f[kk][nt] = f;
    }
#pragma unroll
  for (int kk = 0; kk < 2; ++kk)
#pragma unroll
    for (int nt = 0; nt < 4; ++nt) {
      s8v f;
#pragma unroll
      for (int j = 0; j < 8; ++j)
        f[j] = (short)f2bf(W4[(kk * 32 + q * 8 + j) * 64 + nt * 16 + r]);
      B4f[kk][nt] = f;
    }

  float bias3[4], bias4[4];
#pragma unroll
  for (int nt = 0; nt < 4; ++nt) {
    bias3[nt] = b3[nt * 16 + r];
    bias4[nt] = b4[nt * 16 + r];
  }
  const float al3 = a3p[0];
  const float alb = ablkp[0];

  __shared__ __align__(16) unsigned short hbuf[4][16 * 72];
  unsigned short* hb = hbuf[wv];

  float bs[4] = {0.0f, 0.0f, 0.0f, 0.0f};
  float bq[4] = {0.0f, 0.0f, 0.0f, 0.0f};

  for (int t = wid; t < NN / 16; t += nw) {
    const int n = t * 16 + r;
    const s8v* xn = (const s8v*)(xb + (size_t)n * 64);
    s8v a0  = xn[q];
    s8v a1v = xn[q + 4];
    const float* an = agg + (size_t)n * 64;
    s8v a2v, a3v;
#pragma unroll
    for (int j = 0; j < 8; ++j) a2v[j] = (short)f2bf(an[q * 8 + j]);
#pragma unroll
    for (int j = 0; j < 8; ++j) a3v[j] = (short)f2bf(an[32 + q * 8 + j]);

    f4v acc[4];
#pragma unroll
    for (int nt = 0; nt < 4; ++nt) {
      f4v c = {0.0f, 0.0f, 0.0f, 0.0f};
      c = MFMA16(a0,  B3f[0][nt], c);
      c = MFMA16(a1v, B3f[1][nt], c);
      c = MFMA16(a2v, B3f[2][nt], c);
      c = MFMA16(a3v, B3f[3][nt], c);
      acc[nt] = c;
    }

#pragma unroll
    for (int nt = 0; nt < 4; ++nt)
#pragma unroll
      for (int rg = 0; rg < 4; ++rg) {
        float v = acc[nt][rg] + bias3[nt];
        v = v >= 0.0f ? v : al3 * v;
        hb[(q * 4 + rg) * 72 + nt * 16 + r] = f2bf(v);
      }
    s8v p0 = *(const s8v*)(hb + r * 72 + q * 8);
    s8v p1 = *(const s8v*)(hb + r * 72 + 32 + q * 8);

    f4v acc2[4];
#pragma unroll
    for (int nt = 0; nt < 4; ++nt) {
      f4v c = {0.0f, 0.0f, 0.0f, 0.0f};
      c = MFMA16(p0, B4f[0][nt], c);
      c = MFMA16(p1, B4f[1][nt], c);
      acc2[nt] = c;
    }

#pragma unroll
    for (int nt = 0; nt < 4; ++nt)
#pragma unroll
      for (int rg = 0; rg < 4; ++rg) {
        float v = acc2[nt][rg] + bias4[nt];
        v = v >= 0.0f ? v : alb * v;
        const int row = t * 16 + q * 4 + rg;
        zout[(size_t)row * 64 + nt * 16 + r] = v;
        bs[nt] += v;
        bq[nt] += v * v;
      }
  }

  // reduce BN partials across the 4 quads (col nt*16+r is quad-invariant)
#pragma unroll
  for (int nt = 0; nt < 4; ++nt) {
    float s = bs[nt];
    s += __shfl_xor(s, 16, 64);
    s += __shfl_xor(s, 32, 64);
    float ss = bq[nt];
    ss += __shfl_xor(ss, 16, 64);
    ss += __shfl_xor(ss, 32, 64);
    if (q == 0) {
      atomicAdd(&part[nt * 16 + r], s);
      atomicAdd(&part[64 + nt * 16 + r], ss);
    }
  }
}

// ---------------------------------------------------------------------------
// BatchNorm finalize (in-place, f32): out = (z-mean)*rsqrt(var+eps)*g + b
// ---------------------------------------------------------------------------
__global__ __launch_bounds__(256) void bn_kernel(
    float* __restrict__ out,
    const float* __restrict__ part,
    const float* __restrict__ gamma,
    const float* __restrict__ beta)
{
  const size_t i = (size_t)blockIdx.x * blockDim.x + threadIdx.x;
  if (i * 4 >= (size_t)NN * 64) return;
  float4 v = ((const float4*)out)[i];
  float e[4] = {v.x, v.y, v.z, v.w};
  const int f0 = (int)((i * 4) & 63);
  const float inv_n = 1.0f / (float)NN;
#pragma unroll
  for (int j = 0; j < 4; ++j) {
    const int f = f0 + j;
    const float mean = part[f] * inv_n;
    const float var  = part[64 + f] * inv_n - mean * mean;
    const float sc = rsqrtf(var + BN_EPS) * gamma[f];
    const float sh = beta[f] - mean * sc;
    e[j] = e[j] * sc + sh;
  }
  ((float4*)out)[i] = make_float4(e[0], e[1], e[2], e[3]);
}

extern "C" void kernel_launch(void* const* d_in, const int* in_sizes, int n_in,
                              void* d_out, int out_size, void* d_ws, size_t ws_size,
                              hipStream_t stream) {
  const float* x  = (const float*)d_in[0];
  const int* ei   = (const int*)d_in[1];
  const float* W1 = (const float*)d_in[2];
  const float* b1 = (const float*)d_in[3];
  const float* a1 = (const float*)d_in[4];
  const float* W2 = (const float*)d_in[5];
  const float* b2 = (const float*)d_in[6];
  const float* a2 = (const float*)d_in[7];
  const float* W3 = (const float*)d_in[8];
  const float* b3 = (const float*)d_in[9];
  const float* a3 = (const float*)d_in[10];
  const float* W4 = (const float*)d_in[11];
  const float* b4 = (const float*)d_in[12];
  const float* ab = (const float*)d_in[13];
  const float* gm = (const float*)d_in[14];
  const float* bt = (const float*)d_in[15];

  float* agg          = (float*)d_ws;                    // [NN*64] f32
  float* part         = agg + (size_t)NN * 64;           // [128] f32
  unsigned short* xb  = (unsigned short*)(part + 128);   // [NN*64] bf16
  float* out          = (float*)d_out;

  hipMemsetAsync(d_ws, 0, ((size_t)NN * 64 + 128) * sizeof(float), stream);
  cvt_kernel<<<dim3((NN * 64 / 4 + 255) / 256), dim3(256), 0, stream>>>(x, xb);
  edge_mlp_kernel<<<dim3(1024), dim3(256), 0, stream>>>(xb, ei, W1, b1, a1, W2, b2, a2, agg);
  node_mlp_kernel<<<dim3(256), dim3(256), 0, stream>>>(xb, agg, W3, b3, a3, W4, b4, ab, out, part);
  bn_kernel<<<dim3((NN * 64 / 4 + 255) / 256), dim3(256), 0, stream>>>(out, part, gm, bt);
}